// Round 6
// baseline (4829.535 us; speedup 1.0000x reference)
//
#include <hip/hip_runtime.h>
#include <stdint.h>

typedef __attribute__((ext_vector_type(8))) short short8;
typedef __attribute__((ext_vector_type(4))) float f32x4;

// ---- workspace byte offsets (total ~141.8 MB) ----
#define XB16_OFF  0UL           // bf16 layer input/output [t*64+b][512]   32 MB
#define XP_OFF    33554432UL    // fp16 projections [t][dir][b][gate][u]   96 MB
#define WT_OFF    134217728UL   // bf16 W^T  [3][1536][512]               4.5 MB
#define UT_OFF    138936320UL   // bf16 U^T  [dir*3+l][768][256]         2.25 MB
#define BIASC_OFF 141295616UL   // fp32 input bias (+recur bias for z,r) [3][1536]
#define BRC_OFF   141314048UL   // fp32 recur bias [dir*3+l][768]
#define MASKT_OFF 141332480UL   // byte mask transposed [t][64]           32 KB
#define FLAG_OFF  141725760UL   // mask-dtype flag

#define HB_STRIDE 264           // 256 + 8 pad halves (16B-aligned rows)
#define HBLK (16 * HB_STRIDE)
// LDS: group-2 h-gate U^T table [128][HB_STRIDE] + h double buffer [2][16][HB_STRIDE]
#define LDS_BYTES (((size_t)128 * HB_STRIDE + 2 * HBLK) * 2)

// LDS-only barrier: h double-buffer hazards are all lgkmcnt-counted. Avoids
// __syncthreads' vmcnt(0) drain so global loads/stores ride across steps.
#define LDS_BARRIER() asm volatile("s_waitcnt lgkmcnt(0)\n\ts_barrier" ::: "memory")

// ---- threefry2x32, 20 rounds (jax partitionable mode) ----
__host__ __device__ static inline void tf2x32(unsigned k0, unsigned k1,
                                              unsigned x0, unsigned x1,
                                              unsigned* o0, unsigned* o1) {
  unsigned ks2 = k0 ^ k1 ^ 0x1BD11BDAu;
#define TFR(r) { x0 += x1; x1 = (x1 << (r)) | (x1 >> (32 - (r))); x1 ^= x0; }
  x0 += k0; x1 += k1;
  TFR(13) TFR(15) TFR(26) TFR(6)   x0 += k1;  x1 += ks2 + 1u;
  TFR(17) TFR(29) TFR(16) TFR(24)  x0 += ks2; x1 += k0 + 2u;
  TFR(13) TFR(15) TFR(26) TFR(6)   x0 += k0;  x1 += k1 + 3u;
  TFR(17) TFR(29) TFR(16) TFR(24)  x0 += k1;  x1 += ks2 + 4u;
  TFR(13) TFR(15) TFR(26) TFR(6)   x0 += ks2; x1 += k0 + 5u;
#undef TFR
  *o0 = x0; *o1 = x1;
}

__device__ static inline short f2bf(float f) {  // RNE fp32->bf16
  unsigned u = __float_as_uint(f);
  u = (u + 0x7fffu + ((u >> 16) & 1u)) >> 16;
  return (short)u;
}
__device__ static inline float bf2f(short s) {
  unsigned u = ((unsigned)(unsigned short)s) << 16;
  return __uint_as_float(u);
}
__device__ static inline float cvt_lo(unsigned d) {
  union { unsigned short u; _Float16 h; } c; c.u = (unsigned short)(d & 0xffffu);
  return (float)c.h;
}
__device__ static inline float cvt_hi(unsigned d) {
  union { unsigned short u; _Float16 h; } c; c.u = (unsigned short)(d >> 16);
  return (float)c.h;
}

__global__ void init_k(unsigned* flag) {
  if (threadIdx.x == 0) *flag = 0u;
}

// ---- prep: casts, transposes, tail copy, mask dtype detection ----
__global__ __launch_bounds__(256) void prep_k(
    const float* __restrict__ states, const unsigned* __restrict__ maskw,
    const float* __restrict__ Wf, const float* __restrict__ Uf,
    const float* __restrict__ bf_, const float* __restrict__ Wb,
    const float* __restrict__ Ub, const float* __restrict__ bb_,
    short* __restrict__ xb16, float* __restrict__ dout,
    short* __restrict__ Wt, short* __restrict__ Ut,
    float* __restrict__ biasc, float* __restrict__ brc,
    unsigned* __restrict__ flag) {
  const unsigned gid = blockIdx.x * 256 + threadIdx.x;  // 16,777,216 threads
  {  // states [b*512+t][512] -> xb16 t-major [t*64+b][512]
    unsigned c = gid & 511u, rw = gid >> 9;
    unsigned t = rw >> 6, b = rw & 63u;
    xb16[gid] = f2bf(states[(size_t)(b * 512 + t) * 512 + c]);
  }
  if (gid < 512000u) dout[16777216u + gid] = states[16777216u + gid];  // EXTRA tail
  if (gid < 2359296u) {  // W^T bf16: [l][n(1536)][k(512)]
    unsigned l = gid / 786432u, rem = gid % 786432u;
    unsigned n = rem >> 9, k = rem & 511u;
    float s = (n < 768u) ? Wf[(size_t)(l * 512 + k) * 768 + n]
                         : Wb[(size_t)(l * 512 + k) * 768 + (n - 768u)];
    Wt[gid] = f2bf(s);
  }
  if (gid < 1179648u) {  // U^T bf16: [(dir*3+l)][n(768)][k(256)]
    unsigned g = gid / 196608u, rem = gid % 196608u;
    unsigned dirv = g / 3u, l = g % 3u;
    unsigned n = rem >> 8, k = rem & 255u;
    const float* Usrc = dirv ? Ub : Uf;
    Ut[gid] = f2bf(Usrc[(size_t)(l * 256 + k) * 768 + n]);
  }
  if (gid < 4608u) {  // input bias concat [l][1536]; fold recur bias for z,r gates
    unsigned l = gid / 1536u, n = gid % 1536u;
    unsigned dirv = n / 768u, rem = n % 768u;
    const float* bsrc = dirv ? bb_ : bf_;
    float v = bsrc[(l * 2 + 0) * 768 + rem];
    if (rem < 512u) v += bsrc[(l * 2 + 1) * 768 + rem];   // z,r: additive -> fold
    biasc[gid] = v;
  }
  if (gid < 4608u) {  // recurrent bias [(dir*3+l)][768] (h-gate part used by gru)
    unsigned g = gid / 768u, n = gid % 768u;
    unsigned dirv = g / 3u, l = g % 3u;
    brc[gid] = (dirv ? bb_ : bf_)[(l * 2 + 1) * 768 + n];
  }
  if (gid < 8192u) {  // mask stored as bytes? any word >1 => yes
    if (maskw[gid] > 1u) atomicOr(flag, 1u);
  }
}

// ---- mask transpose: [b][t] (byte or word) -> bytes [t][64] ----
__global__ __launch_bounds__(256) void maskt_k(
    const unsigned char* __restrict__ mask8, const unsigned* __restrict__ flagp,
    unsigned char* __restrict__ maskt) {
  const unsigned gid = blockIdx.x * 256 + threadIdx.x;  // 32768
  const unsigned b = gid >> 9, t = gid & 511u;
  const bool mbyte = (*flagp) != 0u;
  unsigned v = mbyte ? (unsigned)mask8[gid] : ((const unsigned*)mask8)[gid];
  maskt[t * 64 + b] = v ? 1u : 0u;
}

// ---- projection GEMM: [32768,512]bf16 x [512,1536]bf16 -> fp16 + bias ----
// Output layout: xp[t][dir][b][gate][u] fp16 (768 halves per (t,dir,b)):
//   half index = ((t*2+dir)*64 + b)*768 + gate*256 + u
__global__ __launch_bounds__(256) void proj_gemm(
    const short* __restrict__ A, const short* __restrict__ Bt,
    const float* __restrict__ bias, _Float16* __restrict__ C) {
  __shared__ __align__(16) short As[4096];
  __shared__ __align__(16) short Bs[4096];
  const int tid = threadIdx.x;
  const int wave = tid >> 6, lane = tid & 63;
  const int col = lane & 15, kq = lane >> 4;
  const int wr = wave >> 1, wc = wave & 1;
  const int m0 = blockIdx.x * 128, n0 = blockIdx.y * 128;
  const uint4* Aq = (const uint4*)A;
  const uint4* Bq = (const uint4*)Bt;
  uint4* AsQ = (uint4*)As;
  uint4* BsQ = (uint4*)Bs;
  f32x4 acc[4][4];
#pragma unroll
  for (int i = 0; i < 4; ++i)
#pragma unroll
    for (int j = 0; j < 4; ++j) acc[i][j] = (f32x4){0.f, 0.f, 0.f, 0.f};

  for (int kt = 0; kt < 16; ++kt) {
    const int k8 = kt * 4;
#pragma unroll
    for (int rnd = 0; rnd < 2; ++rnd) {
      int chunk = rnd * 256 + tid;
      int row = chunk >> 2, kc = chunk & 3;
      AsQ[chunk] = Aq[(size_t)(m0 + row) * 64 + k8 + kc];
      BsQ[chunk] = Bq[(size_t)(n0 + row) * 64 + k8 + kc];
    }
    __syncthreads();
    short8 af[4], bfv[4];
#pragma unroll
    for (int i = 0; i < 4; ++i)
      af[i] = *(const short8*)(As + (wr * 64 + i * 16 + col) * 32 + kq * 8);
#pragma unroll
    for (int j = 0; j < 4; ++j)
      bfv[j] = *(const short8*)(Bs + (wc * 64 + j * 16 + col) * 32 + kq * 8);
#pragma unroll
    for (int i = 0; i < 4; ++i)
#pragma unroll
      for (int j = 0; j < 4; ++j)
        acc[i][j] = __builtin_amdgcn_mfma_f32_16x16x32_bf16(af[i], bfv[j], acc[i][j], 0, 0, 0);
    __syncthreads();
  }
  // m = m0 + wr*64 + (i*16+kq*4+r): t = m>>6 = (m0>>6)+wr (const), b = i*16+kq*4+r
#pragma unroll
  for (int j = 0; j < 4; ++j) {
    const int cg = n0 + wc * 64 + j * 16 + col;
    const float bv = bias[cg];
    const int dirv = cg / 768, rem = cg % 768;
    const int gate = rem >> 8, u = rem & 255;
    const size_t cbase =
        ((size_t)(((m0 >> 6) + wr) * 2 + dirv)) * 49152 + gate * 256 + u;
#pragma unroll
    for (int i = 0; i < 4; ++i) {
#pragma unroll
      for (int r = 0; r < 4; ++r)
        C[cbase + (size_t)(i * 16 + kq * 4 + r) * 768] = (_Float16)(acc[i][j][r] + bv);
    }
  }
}

// ---- recurrent kernel: 8 blocks x 512 threads (8 waves, 2 waves/SIMD) ----
// Wave w owns 32 units (two m-tiles). 256-reg budget at 2 waves/SIMD lets
// 5 of 6 weight tiles (zA x2, rA x2, hA group-1) live in registers; only the
// group-2 h-gate tile streams from a 128-row LDS table. The shared h-state
// B-fragment (8 ds_read_b128/thread) feeds all 6 MFMA chains -> per-CU LDS
// instr halves vs the 16-wave version (128 vs 256 per step).
__global__ __launch_bounds__(512, 2) void gru32(
    const _Float16* __restrict__ xp, const short* __restrict__ UtAll,
    const float* __restrict__ brcAll, const unsigned char* __restrict__ maskt,
    short* __restrict__ yout, int layer) {
  extern __shared__ short lds[];
  short* hgate = lds;                       // [128][HB_STRIDE] group-2 h-gate U^T
  short* hbuf  = lds + 128 * HB_STRIDE;     // [2][16][HB_STRIDE] h state (bf16)

  const int bid = blockIdx.x;
  const int dir = bid >> 2;
  const int b0 = (bid & 3) * 16;
  const int tid = threadIdx.x;
  const int wave = tid >> 6, lane = tid & 63;
  const int col = lane & 15, quad = lane >> 4;
  const short* Ut = UtAll + (size_t)(dir * 3 + layer) * 768 * 256;
  const float* brc = brcAll + (dir * 3 + layer) * 768;

  // stage group-2 h-gate rows: table row r <-> unit (r>>4)*32 + 16 + (r&15)
  const short* Uth = Ut + 512 * 256;
  for (int c = tid; c < 4096; c += 512) {
    int row = c >> 5, q = c & 31;
    int u = ((row >> 4) << 5) + 16 + (row & 15);
    *(uint4*)(hgate + row * HB_STRIDE + q * 8) = *(const uint4*)(Uth + u * 256 + q * 8);
  }
  for (int i = tid; i < 2 * HBLK; i += 512) hbuf[i] = 0;

  // resident A-frags: lane (col,quad) holds A[m=col][k=quad*8+j+ks*32]
  short8 zA1[8], zA2[8], rA1[8], rA2[8], hA1[8];
  const int m1 = wave * 32 + col;
#pragma unroll
  for (int ks = 0; ks < 8; ++ks) {
    const int ko = ks * 32 + quad * 8;
    zA1[ks] = *(const short8*)(Ut + (size_t)m1 * 256 + ko);
    zA2[ks] = *(const short8*)(Ut + (size_t)(m1 + 16) * 256 + ko);
    rA1[ks] = *(const short8*)(Ut + (size_t)(256 + m1) * 256 + ko);
    rA2[ks] = *(const short8*)(Ut + (size_t)(256 + m1 + 16) * 256 + ko);
    hA1[ks] = *(const short8*)(Ut + (size_t)(512 + m1) * 256 + ko);
  }
  const int u0 = wave * 32 + quad * 4;      // group-1 first owned unit
  f32x4 brh1, brh2;
#pragma unroll
  for (int r = 0; r < 4; ++r) {
    brh1[r] = brc[512 + u0 + r];
    brh2[r] = brc[512 + u0 + 16 + r];
  }

  // xp addressing (bytes): base = ((t*2+dir)*64 + b)*1536 + u0_in_dir*2
  //   group1: z +0, r +512, h +1024 ; group2: +32 on each (imm offsets)
  const int t0 = dir ? 511 : 0;
  const int tstep = dir ? -1 : 1;
  const char* xpb = (const char*)xp;
  const int gb = b0 + col;                  // global batch row for this thread
  unsigned xaddr = (unsigned)(((t0 * 2 + dir) * 64 + gb) * 1536 + wave * 64 + quad * 8);
  const int xstep = tstep * 196608;         // 2*64*1536

  // LDS lane offsets (halves)
  const short* hg2 = hgate + (wave * 16 + col) * HB_STRIDE + quad * 8;
  const int rd_lane = col * HB_STRIDE + quad * 8;
  const int wr_lane = col * HB_STRIDE + u0;  // group2 at +16

  // y addressing (bytes): (t*64+b)*1024 + dir*512 + u0*2 ; group2 +32
  unsigned yoff = (unsigned)((t0 * 64 + gb) * 1024 + dir * 512 + u0 * 2);
  const int ystep = tstep * 65536;
  int moff = t0 * 64 + gb;

  // prologue prefetch for s=0
  uint2 pz1, pz2, pr1, pr2, ph1, ph2;
  unsigned pm;
  pz1 = *(const uint2*)(xpb + xaddr);
  pz2 = *(const uint2*)(xpb + xaddr + 32);
  pr1 = *(const uint2*)(xpb + xaddr + 512);
  pr2 = *(const uint2*)(xpb + xaddr + 544);
  ph1 = *(const uint2*)(xpb + xaddr + 1024);
  ph2 = *(const uint2*)(xpb + xaddr + 1056);
  pm = maskt[moff];

  float hp[8] = {0.f, 0.f, 0.f, 0.f, 0.f, 0.f, 0.f, 0.f};
  __syncthreads();

  for (int s = 0; s < 512; ++s) {
    // init accumulators from prefetched projections (z,r) and recur bias (h)
    f32x4 az1, az2, ar1, ar2, ah1, ah2;
    az1[0] = cvt_lo(pz1.x); az1[1] = cvt_hi(pz1.x);
    az1[2] = cvt_lo(pz1.y); az1[3] = cvt_hi(pz1.y);
    az2[0] = cvt_lo(pz2.x); az2[1] = cvt_hi(pz2.x);
    az2[2] = cvt_lo(pz2.y); az2[3] = cvt_hi(pz2.y);
    ar1[0] = cvt_lo(pr1.x); ar1[1] = cvt_hi(pr1.x);
    ar1[2] = cvt_lo(pr1.y); ar1[3] = cvt_hi(pr1.y);
    ar2[0] = cvt_lo(pr2.x); ar2[1] = cvt_hi(pr2.x);
    ar2[2] = cvt_lo(pr2.y); ar2[3] = cvt_hi(pr2.y);
    ah1 = brh1; ah2 = brh2;
    float xh[8];
    xh[0] = cvt_lo(ph1.x); xh[1] = cvt_hi(ph1.x);
    xh[2] = cvt_lo(ph1.y); xh[3] = cvt_hi(ph1.y);
    xh[4] = cvt_lo(ph2.x); xh[5] = cvt_hi(ph2.x);
    xh[6] = cvt_lo(ph2.y); xh[7] = cvt_hi(ph2.y);
    const bool mv = (pm != 0u);
    // issue next-step prefetch (consumed at next init)
    if (s < 511) {
      xaddr += xstep;
      pz1 = *(const uint2*)(xpb + xaddr);
      pz2 = *(const uint2*)(xpb + xaddr + 32);
      pr1 = *(const uint2*)(xpb + xaddr + 512);
      pr2 = *(const uint2*)(xpb + xaddr + 544);
      ph1 = *(const uint2*)(xpb + xaddr + 1024);
      ph2 = *(const uint2*)(xpb + xaddr + 1056);
      moff += tstep * 64;
      pm = maskt[moff];
    }

    // recurrent matmul: shared h-state B-frag feeds all 6 chains
    const short* hrd = hbuf + (s & 1) * HBLK + rd_lane;
#pragma unroll
    for (int ks = 0; ks < 8; ++ks) {
      short8 hbv = *(const short8*)(hrd + ks * 32);
      short8 h2  = *(const short8*)(hg2 + ks * 32);
      az1 = __builtin_amdgcn_mfma_f32_16x16x32_bf16(zA1[ks], hbv, az1, 0, 0, 0);
      az2 = __builtin_amdgcn_mfma_f32_16x16x32_bf16(zA2[ks], hbv, az2, 0, 0, 0);
      ar1 = __builtin_amdgcn_mfma_f32_16x16x32_bf16(rA1[ks], hbv, ar1, 0, 0, 0);
      ar2 = __builtin_amdgcn_mfma_f32_16x16x32_bf16(rA2[ks], hbv, ar2, 0, 0, 0);
      ah1 = __builtin_amdgcn_mfma_f32_16x16x32_bf16(hA1[ks], hbv, ah1, 0, 0, 0);
      ah2 = __builtin_amdgcn_mfma_f32_16x16x32_bf16(h2,      hbv, ah2, 0, 0, 0);
    }

    // epilogue: 2 groups x 4 consecutive units for one batch row
    float hn[8];
#pragma unroll
    for (int r = 0; r < 4; ++r) {
      float z  = 1.f / (1.f + __builtin_amdgcn_exp2f(az1[r] * -1.44269504f));
      float rr = 1.f / (1.f + __builtin_amdgcn_exp2f(ar1[r] * -1.44269504f));
      float pre = xh[r] + rr * ah1[r];
      float hc = 1.f - 2.f / (__builtin_amdgcn_exp2f(pre * 2.88539008f) + 1.f);
      float hpv = hp[r];
      float v = hc + z * (hpv - hc);
      hn[r] = mv ? v : hpv;
      hp[r] = hn[r];
    }
#pragma unroll
    for (int r = 0; r < 4; ++r) {
      float z  = 1.f / (1.f + __builtin_amdgcn_exp2f(az2[r] * -1.44269504f));
      float rr = 1.f / (1.f + __builtin_amdgcn_exp2f(ar2[r] * -1.44269504f));
      float pre = xh[4 + r] + rr * ah2[r];
      float hc = 1.f - 2.f / (__builtin_amdgcn_exp2f(pre * 2.88539008f) + 1.f);
      float hpv = hp[4 + r];
      float v = hc + z * (hpv - hc);
      hn[4 + r] = mv ? v : hpv;
      hp[4 + r] = hn[4 + r];
    }
    uint2 pk1, pk2;
    asm("v_cvt_pk_bf16_f32 %0, %1, %2" : "=v"(pk1.x) : "v"(hn[0]), "v"(hn[1]));
    asm("v_cvt_pk_bf16_f32 %0, %1, %2" : "=v"(pk1.y) : "v"(hn[2]), "v"(hn[3]));
    asm("v_cvt_pk_bf16_f32 %0, %1, %2" : "=v"(pk2.x) : "v"(hn[4]), "v"(hn[5]));
    asm("v_cvt_pk_bf16_f32 %0, %1, %2" : "=v"(pk2.y) : "v"(hn[6]), "v"(hn[7]));
    short* hwr = hbuf + ((s & 1) ^ 1) * HBLK + wr_lane;
    *(uint2*)(hwr) = pk1;
    *(uint2*)(hwr + 16) = pk2;
    char* yb = (char*)yout + yoff;
    *(uint2*)(yb) = pk1;
    *(uint2*)(yb + 32) = pk2;
    yoff += ystep;
    // LDS-only barrier (no vmcnt drain): global ops stay in flight
    LDS_BARRIER();
  }
}

// ---- dropout (JAX threefry partitionable); j == gid (t-major) ----
__global__ __launch_bounds__(256) void drop_k(
    short* __restrict__ xb16, float* __restrict__ dout,
    const int* __restrict__ training, unsigned k0, unsigned k1, int last) {
  const unsigned gid = blockIdx.x * 256 + threadIdx.x;
  float v = bf2f(xb16[gid]);
  unsigned y0, y1;
  tf2x32(k0, k1, 0u, gid, &y0, &y1);
  unsigned bits = y0 ^ y1;
  float u = __uint_as_float((bits >> 9) | 0x3f800000u) - 1.0f;
  bool keep = u < 0.9f;
  int tr = *training;
  float ov = tr ? (keep ? v * (1.0f / 0.9f) : 0.0f) : v;
  if (last) {
    unsigned r = gid >> 9, c = gid & 511u;
    unsigned t = r >> 6, b = r & 63u;
    dout[(size_t)(b * 512 + t) * 512 + c] = ov;
  } else {
    xb16[gid] = f2bf(ov);
  }
}

extern "C" void kernel_launch(void* const* d_in, const int* in_sizes, int n_in,
                              void* d_out, int out_size, void* d_ws, size_t ws_size,
                              hipStream_t stream) {
  (void)in_sizes; (void)n_in; (void)out_size; (void)ws_size;
  const float* states = (const float*)d_in[0];
  const void*  mask   = d_in[1];
  const int*   training = (const int*)d_in[3];
  const float* Wf = (const float*)d_in[4];
  const float* Uf = (const float*)d_in[5];
  const float* bf_ = (const float*)d_in[6];
  const float* Wb = (const float*)d_in[7];
  const float* Ub = (const float*)d_in[8];
  const float* bb_ = (const float*)d_in[9];
  char* ws = (char*)d_ws;

  short* xb16   = (short*)(ws + XB16_OFF);
  _Float16* xp  = (_Float16*)(ws + XP_OFF);
  short* Wt     = (short*)(ws + WT_OFF);
  short* Ut     = (short*)(ws + UT_OFF);
  float* biasc  = (float*)(ws + BIASC_OFF);
  float* brc    = (float*)(ws + BRC_OFF);
  unsigned char* maskt = (unsigned char*)(ws + MASKT_OFF);
  unsigned* flag = (unsigned*)(ws + FLAG_OFF);
  float* dout = (float*)d_out;

  // allow >64KB dynamic LDS for gru32 (idempotent; not a stream op)
  hipFuncSetAttribute((const void*)gru32,
                      hipFuncAttributeMaxDynamicSharedMemorySize, (int)LDS_BYTES);

  // threefry key chain: key(1234); per layer: dkey,sk = split(dkey)
  unsigned d0 = 0u, d1 = 1234u, sk0[3], sk1[3];
  for (int l = 0; l < 3; ++l) {
    unsigned a, b, c, d;
    tf2x32(d0, d1, 0u, 0u, &a, &b);   // new dkey
    tf2x32(d0, d1, 0u, 1u, &c, &d);   // subkey
    sk0[l] = c; sk1[l] = d;
    d0 = a; d1 = b;
  }

  init_k<<<1, 64, 0, stream>>>(flag);
  prep_k<<<65536, 256, 0, stream>>>(states, (const unsigned*)mask, Wf, Uf, bf_,
                                    Wb, Ub, bb_, xb16, dout, Wt, Ut, biasc, brc, flag);
  maskt_k<<<128, 256, 0, stream>>>((const unsigned char*)mask, flag, maskt);
  for (int l = 0; l < 3; ++l) {
    proj_gemm<<<dim3(256, 12), 256, 0, stream>>>(xb16, Wt + (size_t)l * 1536 * 512,
                                                 biasc + l * 1536, xp);
    gru32<<<8, 512, LDS_BYTES, stream>>>(xp, Ut, brc, maskt, xb16, l);
    drop_k<<<65536, 256, 0, stream>>>(xb16, dout, training, sk0[l], sk1[l], l == 2);
  }
}

// Round 7
// 4556.365 us; speedup vs baseline: 1.0600x; 1.0600x over previous
//
#include <hip/hip_runtime.h>
#include <stdint.h>

typedef __attribute__((ext_vector_type(8))) short short8;
typedef __attribute__((ext_vector_type(4))) float f32x4;

// ---- workspace byte offsets (total ~141.8 MB) ----
#define XB16_OFF  0UL           // bf16 layer input/output [t*64+b][512]   32 MB
#define XP_OFF    33554432UL    // fp16 projections [t][dir][b][gate][u]   96 MB
#define WT_OFF    134217728UL   // bf16 W^T  [3][1536][512]               4.5 MB
#define UT_OFF    138936320UL   // bf16 U^T  [dir*3+l][768][256]         2.25 MB
#define BIASC_OFF 141295616UL   // fp32 input bias (+recur bias for z,r) [3][1536]
#define BRC_OFF   141314048UL   // fp32 recur bias [dir*3+l][768]
#define MASKT_OFF 141332480UL   // byte mask transposed [t][64]           32 KB
#define FLAG_OFF  141725760UL   // mask-dtype flag

#define HB_STRIDE 264           // 256 + 8 pad halves (conflict-free b128 reads)
#define HBLK (16 * HB_STRIDE)
#define HG_STRIDE 136           // 128 + 8 pad halves (h-gate upper-K table)
// LDS: h-gate U^T upper-K [256][HG_STRIDE] + h double buffer [2][16][HB_STRIDE]
#define LDS_BYTES (((size_t)256 * HG_STRIDE + 2 * HBLK) * 2)

// LDS-only barrier: h double-buffer hazards are all lgkmcnt-counted. Avoids
// __syncthreads' vmcnt(0) drain so global loads/stores ride across steps.
#define LDS_BARRIER() asm volatile("s_waitcnt lgkmcnt(0)\n\ts_barrier" ::: "memory")

// async global->LDS (16B per lane; LDS dst = wave-uniform base + lane*16)
typedef __attribute__((address_space(1))) const unsigned int* as1_u32p;
typedef __attribute__((address_space(3))) unsigned int* as3_u32p;
#define GLOBAL_TO_LDS16(g, l) \
  __builtin_amdgcn_global_load_lds((as1_u32p)(g), (as3_u32p)(l), 16, 0, 0)

// ---- threefry2x32, 20 rounds (jax partitionable mode) ----
__host__ __device__ static inline void tf2x32(unsigned k0, unsigned k1,
                                              unsigned x0, unsigned x1,
                                              unsigned* o0, unsigned* o1) {
  unsigned ks2 = k0 ^ k1 ^ 0x1BD11BDAu;
#define TFR(r) { x0 += x1; x1 = (x1 << (r)) | (x1 >> (32 - (r))); x1 ^= x0; }
  x0 += k0; x1 += k1;
  TFR(13) TFR(15) TFR(26) TFR(6)   x0 += k1;  x1 += ks2 + 1u;
  TFR(17) TFR(29) TFR(16) TFR(24)  x0 += ks2; x1 += k0 + 2u;
  TFR(13) TFR(15) TFR(26) TFR(6)   x0 += k0;  x1 += k1 + 3u;
  TFR(17) TFR(29) TFR(16) TFR(24)  x0 += k1;  x1 += ks2 + 4u;
  TFR(13) TFR(15) TFR(26) TFR(6)   x0 += ks2; x1 += k0 + 5u;
#undef TFR
  *o0 = x0; *o1 = x1;
}

__device__ static inline short f2bf(float f) {  // RNE fp32->bf16
  unsigned u = __float_as_uint(f);
  u = (u + 0x7fffu + ((u >> 16) & 1u)) >> 16;
  return (short)u;
}
__device__ static inline float bf2f(short s) {
  unsigned u = ((unsigned)(unsigned short)s) << 16;
  return __uint_as_float(u);
}
__device__ static inline float cvt_lo(unsigned d) {
  union { unsigned short u; _Float16 h; } c; c.u = (unsigned short)(d & 0xffffu);
  return (float)c.h;
}
__device__ static inline float cvt_hi(unsigned d) {
  union { unsigned short u; _Float16 h; } c; c.u = (unsigned short)(d >> 16);
  return (float)c.h;
}

__global__ void init_k(unsigned* flag) {
  if (threadIdx.x == 0) *flag = 0u;
}

// ---- prep: casts, transposes, tail copy, mask dtype detection ----
__global__ __launch_bounds__(256) void prep_k(
    const float* __restrict__ states, const unsigned* __restrict__ maskw,
    const float* __restrict__ Wf, const float* __restrict__ Uf,
    const float* __restrict__ bf_, const float* __restrict__ Wb,
    const float* __restrict__ Ub, const float* __restrict__ bb_,
    short* __restrict__ xb16, float* __restrict__ dout,
    short* __restrict__ Wt, short* __restrict__ Ut,
    float* __restrict__ biasc, float* __restrict__ brc,
    unsigned* __restrict__ flag) {
  const unsigned gid = blockIdx.x * 256 + threadIdx.x;  // 16,777,216 threads
  {  // states [b*512+t][512] -> xb16 t-major [t*64+b][512]
    unsigned c = gid & 511u, rw = gid >> 9;
    unsigned t = rw >> 6, b = rw & 63u;
    xb16[gid] = f2bf(states[(size_t)(b * 512 + t) * 512 + c]);
  }
  if (gid < 512000u) dout[16777216u + gid] = states[16777216u + gid];  // EXTRA tail
  if (gid < 2359296u) {  // W^T bf16: [l][n(1536)][k(512)]
    unsigned l = gid / 786432u, rem = gid % 786432u;
    unsigned n = rem >> 9, k = rem & 511u;
    float s = (n < 768u) ? Wf[(size_t)(l * 512 + k) * 768 + n]
                         : Wb[(size_t)(l * 512 + k) * 768 + (n - 768u)];
    Wt[gid] = f2bf(s);
  }
  if (gid < 1179648u) {  // U^T bf16: [(dir*3+l)][n(768)][k(256)]
    unsigned g = gid / 196608u, rem = gid % 196608u;
    unsigned dirv = g / 3u, l = g % 3u;
    unsigned n = rem >> 8, k = rem & 255u;
    const float* Usrc = dirv ? Ub : Uf;
    Ut[gid] = f2bf(Usrc[(size_t)(l * 256 + k) * 768 + n]);
  }
  if (gid < 4608u) {  // input bias concat [l][1536]; fold recur bias for z,r gates
    unsigned l = gid / 1536u, n = gid % 1536u;
    unsigned dirv = n / 768u, rem = n % 768u;
    const float* bsrc = dirv ? bb_ : bf_;
    float v = bsrc[(l * 2 + 0) * 768 + rem];
    if (rem < 512u) v += bsrc[(l * 2 + 1) * 768 + rem];   // z,r: additive -> fold
    biasc[gid] = v;
  }
  if (gid < 4608u) {  // recurrent bias [(dir*3+l)][768] (h-gate part used by gru)
    unsigned g = gid / 768u, n = gid % 768u;
    unsigned dirv = g / 3u, l = g % 3u;
    brc[gid] = (dirv ? bb_ : bf_)[(l * 2 + 1) * 768 + n];
  }
  if (gid < 8192u) {  // mask stored as bytes? any word >1 => yes
    if (maskw[gid] > 1u) atomicOr(flag, 1u);
  }
}

// ---- mask transpose: [b][t] (byte or word) -> bytes [t][64] ----
__global__ __launch_bounds__(256) void maskt_k(
    const unsigned char* __restrict__ mask8, const unsigned* __restrict__ flagp,
    unsigned char* __restrict__ maskt) {
  const unsigned gid = blockIdx.x * 256 + threadIdx.x;  // 32768
  const unsigned b = gid >> 9, t = gid & 511u;
  const bool mbyte = (*flagp) != 0u;
  unsigned v = mbyte ? (unsigned)mask8[gid] : ((const unsigned*)mask8)[gid];
  maskt[t * 64 + b] = v ? 1u : 0u;
}

// ---- projection GEMM: [32768,512]bf16 x [512,1536]bf16 -> fp16 + bias ----
// Staging via global_load_lds (async direct-to-LDS, 16B/lane).
// Output layout: xp[t][dir][b][gate][u] fp16:
//   half index = ((t*2+dir)*64 + b)*768 + gate*256 + u
__global__ __launch_bounds__(256) void proj_gemm(
    const short* __restrict__ A, const short* __restrict__ Bt,
    const float* __restrict__ bias, _Float16* __restrict__ C) {
  __shared__ __align__(16) short As[4096];
  __shared__ __align__(16) short Bs[4096];
  const int tid = threadIdx.x;
  const int wave = tid >> 6, lane = tid & 63;
  const int col = lane & 15, kq = lane >> 4;
  const int wr = wave >> 1, wc = wave & 1;
  const int m0 = blockIdx.x * 128, n0 = blockIdx.y * 128;
  const uint4* Aq = (const uint4*)A;
  const uint4* Bq = (const uint4*)Bt;
  f32x4 acc[4][4];
#pragma unroll
  for (int i = 0; i < 4; ++i)
#pragma unroll
    for (int j = 0; j < 4; ++j) acc[i][j] = (f32x4){0.f, 0.f, 0.f, 0.f};

  for (int kt = 0; kt < 16; ++kt) {
    const int k8 = kt * 4;
    // async stage: per wave, 64 lanes x 16B contiguous in LDS; global src per-lane
#pragma unroll
    for (int rnd = 0; rnd < 2; ++rnd) {
      const int chunk = rnd * 256 + wave * 64 + lane;
      const int row = chunk >> 2, kc = chunk & 3;
      const int base = (rnd * 256 + wave * 64) * 8;  // halves, wave-uniform
      GLOBAL_TO_LDS16(&Aq[(size_t)(m0 + row) * 64 + k8 + kc], As + base);
      GLOBAL_TO_LDS16(&Bq[(size_t)(n0 + row) * 64 + k8 + kc], Bs + base);
    }
    __syncthreads();   // drains vmcnt (global_load_lds) + barrier
    short8 af[4], bfv[4];
#pragma unroll
    for (int i = 0; i < 4; ++i)
      af[i] = *(const short8*)(As + (wr * 64 + i * 16 + col) * 32 + kq * 8);
#pragma unroll
    for (int j = 0; j < 4; ++j)
      bfv[j] = *(const short8*)(Bs + (wc * 64 + j * 16 + col) * 32 + kq * 8);
#pragma unroll
    for (int i = 0; i < 4; ++i)
#pragma unroll
      for (int j = 0; j < 4; ++j)
        acc[i][j] = __builtin_amdgcn_mfma_f32_16x16x32_bf16(af[i], bfv[j], acc[i][j], 0, 0, 0);
    __syncthreads();
  }
  // m = m0 + wr*64 + (i*16+kq*4+r): t = (m0>>6)+wr (const), b = i*16+kq*4+r
#pragma unroll
  for (int j = 0; j < 4; ++j) {
    const int cg = n0 + wc * 64 + j * 16 + col;
    const float bv = bias[cg];
    const int dirv = cg / 768, rem = cg % 768;
    const int gate = rem >> 8, u = rem & 255;
    const size_t cbase =
        ((size_t)(((m0 >> 6) + wr) * 2 + dirv)) * 49152 + gate * 256 + u;
#pragma unroll
    for (int i = 0; i < 4; ++i) {
#pragma unroll
      for (int r = 0; r < 4; ++r)
        C[cbase + (size_t)(i * 16 + kq * 4 + r) * 768] = (_Float16)(acc[i][j][r] + bv);
    }
  }
}

// ---- recurrent kernel: 8 blocks x 1024 threads (16 waves, 4 waves/SIMD) ----
// TRANSPOSED mapping: D[m=unit][n=batch]. Wave w owns units [w*16,w*16+16).
// Register budget (128/thread at 4 waves/SIMD) now holds 2.5 of 3 gate
// weight tiles: zA[8] + rA[8] + hA[0..4) (80 regs); only the h-gate UPPER-K
// half streams from LDS -> 12 ds_read_b128/thread/step (was 16). xp loads
// moved in-step (consumed in epilogue; acc init = 0/brh) to free the
// prefetch registers.
__global__ __launch_bounds__(1024, 4) void gru16(
    const _Float16* __restrict__ xp, const short* __restrict__ UtAll,
    const float* __restrict__ brcAll, const unsigned char* __restrict__ maskt,
    short* __restrict__ yout, int layer) {
  extern __shared__ short lds[];
  short* hgate = lds;                       // [256][HG_STRIDE] h-gate U^T, K in [128,256)
  short* hbuf  = lds + 256 * HG_STRIDE;     // [2][16][HB_STRIDE] h state (bf16)

  const int bid = blockIdx.x;
  const int dir = bid >> 2;
  const int b0 = (bid & 3) * 16;
  const int tid = threadIdx.x;
  const int wave = tid >> 6, lane = tid & 63;
  const int col = lane & 15, quad = lane >> 4;
  const int u0 = wave * 16 + quad * 4;      // first owned unit
  const short* Ut = UtAll + (size_t)(dir * 3 + layer) * 768 * 256;
  const float* brc = brcAll + (dir * 3 + layer) * 768;

  // stage h-gate U^T upper-K half: hgate[row][k'] = Uth[row][128+k']
  const short* Uth = Ut + 512 * 256;
  for (int c = tid; c < 4096; c += 1024) {
    int row = c >> 4, q = c & 15;
    *(uint4*)(hgate + row * HG_STRIDE + q * 8) =
        *(const uint4*)(Uth + row * 256 + 128 + q * 8);
  }
  for (int i = tid; i < 2 * HBLK; i += 1024) hbuf[i] = 0;

  // resident A-frags: lane (col,quad) holds A[m=col][k=quad*8+j+ks*32]
  short8 zA[8], rA[8], hA[4];
#pragma unroll
  for (int ks = 0; ks < 8; ++ks) {
    zA[ks] = *(const short8*)(Ut + (size_t)(wave * 16 + col) * 256 + ks * 32 + quad * 8);
    rA[ks] = *(const short8*)(Ut + (size_t)(256 + wave * 16 + col) * 256 + ks * 32 + quad * 8);
  }
#pragma unroll
  for (int ks = 0; ks < 4; ++ks)
    hA[ks] = *(const short8*)(Ut + (size_t)(512 + wave * 16 + col) * 256 + ks * 32 + quad * 8);
  f32x4 brh;
#pragma unroll
  for (int r = 0; r < 4; ++r) brh[r] = brc[512 + u0 + r];

  // xp addressing (bytes): base = ((t*2+dir)*64 + b)*1536 + u0_in_dir*2
  //   z at +0, r at +512, h at +1024 (imm offsets)
  const int t0 = dir ? 511 : 0;
  const int tstep = dir ? -1 : 1;
  const char* xpb = (const char*)xp;
  const int gb = b0 + col;                  // global batch row for this thread
  unsigned xaddr = (unsigned)(((t0 * 2 + dir) * 64 + gb) * 1536 + wave * 32 + quad * 8);
  const int xstep = tstep * 196608;         // 2*64*1536

  // LDS lane offsets (halves)
  const short* hgL = hgate + (wave * 16 + col) * HG_STRIDE + quad * 8;
  const int rd_lane = col * HB_STRIDE + quad * 8;
  const int wr_lane = col * HB_STRIDE + u0;

  // y addressing (bytes): (t*64+b)*1024 + dir*512 + u0*2
  unsigned yoff = (unsigned)((t0 * 64 + gb) * 1024 + dir * 512 + u0 * 2);
  const int ystep = tstep * 65536;
  int moff = t0 * 64 + gb;

  float hp[4] = {0.f, 0.f, 0.f, 0.f};
  __syncthreads();

  for (int s = 0; s < 512; ++s) {
    // in-step xp/mask loads: issue now, consumed only in the epilogue
    // (latency hides under the MFMA+LDS phase)
    uint2 pz = *(const uint2*)(xpb + xaddr);
    uint2 pr = *(const uint2*)(xpb + xaddr + 512);
    uint2 ph = *(const uint2*)(xpb + xaddr + 1024);
    unsigned pm = maskt[moff];

    // acc init: z/r biases are folded into xp (added in epilogue)
    f32x4 az = {0.f, 0.f, 0.f, 0.f};
    f32x4 ar = {0.f, 0.f, 0.f, 0.f};
    f32x4 ah = brh;

    // recurrent matmul: A=U^T (z/r + h-lowK in regs, h-highK from LDS),
    // B=h(t-1) from LDS
    const short* hrd = hbuf + (s & 1) * HBLK + rd_lane;
#pragma unroll
    for (int ks = 0; ks < 8; ++ks) {
      short8 hbv = *(const short8*)(hrd + ks * 32);
      short8 hg  = (ks < 4) ? hA[ks] : *(const short8*)(hgL + (ks - 4) * 32);
      az = __builtin_amdgcn_mfma_f32_16x16x32_bf16(zA[ks], hbv, az, 0, 0, 0);
      ar = __builtin_amdgcn_mfma_f32_16x16x32_bf16(rA[ks], hbv, ar, 0, 0, 0);
      ah = __builtin_amdgcn_mfma_f32_16x16x32_bf16(hg,     hbv, ah, 0, 0, 0);
    }

    // epilogue: 4 consecutive units for one batch row
    const bool mv = (pm != 0u);
    float xz[4], xr[4], xh[4];
    xz[0] = cvt_lo(pz.x); xz[1] = cvt_hi(pz.x);
    xz[2] = cvt_lo(pz.y); xz[3] = cvt_hi(pz.y);
    xr[0] = cvt_lo(pr.x); xr[1] = cvt_hi(pr.x);
    xr[2] = cvt_lo(pr.y); xr[3] = cvt_hi(pr.y);
    xh[0] = cvt_lo(ph.x); xh[1] = cvt_hi(ph.x);
    xh[2] = cvt_lo(ph.y); xh[3] = cvt_hi(ph.y);
    float hn[4];
#pragma unroll
    for (int r = 0; r < 4; ++r) {
      float z  = 1.f / (1.f + __builtin_amdgcn_exp2f((az[r] + xz[r]) * -1.44269504f));
      float rr = 1.f / (1.f + __builtin_amdgcn_exp2f((ar[r] + xr[r]) * -1.44269504f));
      float pre = xh[r] + rr * ah[r];
      float hc = 1.f - 2.f / (__builtin_amdgcn_exp2f(pre * 2.88539008f) + 1.f);
      float hpv = hp[r];
      float v = hc + z * (hpv - hc);
      hn[r] = mv ? v : hpv;
      hp[r] = hn[r];
    }
    uint2 packed;
    asm("v_cvt_pk_bf16_f32 %0, %1, %2" : "=v"(packed.x) : "v"(hn[0]), "v"(hn[1]));
    asm("v_cvt_pk_bf16_f32 %0, %1, %2" : "=v"(packed.y) : "v"(hn[2]), "v"(hn[3]));
    *(uint2*)(hbuf + ((s & 1) ^ 1) * HBLK + wr_lane) = packed;
    *(uint2*)((char*)yout + yoff) = packed;
    yoff += ystep;
    xaddr += xstep;
    moff += tstep * 64;
    // LDS-only barrier (no vmcnt drain): global ops stay in flight
    LDS_BARRIER();
  }
}

// ---- dropout (JAX threefry partitionable); j == gid (t-major) ----
__global__ __launch_bounds__(256) void drop_k(
    short* __restrict__ xb16, float* __restrict__ dout,
    const int* __restrict__ training, unsigned k0, unsigned k1, int last) {
  const unsigned gid = blockIdx.x * 256 + threadIdx.x;
  float v = bf2f(xb16[gid]);
  unsigned y0, y1;
  tf2x32(k0, k1, 0u, gid, &y0, &y1);
  unsigned bits = y0 ^ y1;
  float u = __uint_as_float((bits >> 9) | 0x3f800000u) - 1.0f;
  bool keep = u < 0.9f;
  int tr = *training;
  float ov = tr ? (keep ? v * (1.0f / 0.9f) : 0.0f) : v;
  if (last) {
    unsigned r = gid >> 9, c = gid & 511u;
    unsigned t = r >> 6, b = r & 63u;
    dout[(size_t)(b * 512 + t) * 512 + c] = ov;
  } else {
    xb16[gid] = f2bf(ov);
  }
}

extern "C" void kernel_launch(void* const* d_in, const int* in_sizes, int n_in,
                              void* d_out, int out_size, void* d_ws, size_t ws_size,
                              hipStream_t stream) {
  (void)in_sizes; (void)n_in; (void)out_size; (void)ws_size;
  const float* states = (const float*)d_in[0];
  const void*  mask   = d_in[1];
  const int*   training = (const int*)d_in[3];
  const float* Wf = (const float*)d_in[4];
  const float* Uf = (const float*)d_in[5];
  const float* bf_ = (const float*)d_in[6];
  const float* Wb = (const float*)d_in[7];
  const float* Ub = (const float*)d_in[8];
  const float* bb_ = (const float*)d_in[9];
  char* ws = (char*)d_ws;

  short* xb16   = (short*)(ws + XB16_OFF);
  _Float16* xp  = (_Float16*)(ws + XP_OFF);
  short* Wt     = (short*)(ws + WT_OFF);
  short* Ut     = (short*)(ws + UT_OFF);
  float* biasc  = (float*)(ws + BIASC_OFF);
  float* brc    = (float*)(ws + BRC_OFF);
  unsigned char* maskt = (unsigned char*)(ws + MASKT_OFF);
  unsigned* flag = (unsigned*)(ws + FLAG_OFF);
  float* dout = (float*)d_out;

  // allow >64KB dynamic LDS for gru16 (idempotent; not a stream op)
  hipFuncSetAttribute((const void*)gru16,
                      hipFuncAttributeMaxDynamicSharedMemorySize, (int)LDS_BYTES);

  // threefry key chain: key(1234); per layer: dkey,sk = split(dkey)
  unsigned d0 = 0u, d1 = 1234u, sk0[3], sk1[3];
  for (int l = 0; l < 3; ++l) {
    unsigned a, b, c, d;
    tf2x32(d0, d1, 0u, 0u, &a, &b);   // new dkey
    tf2x32(d0, d1, 0u, 1u, &c, &d);   // subkey
    sk0[l] = c; sk1[l] = d;
    d0 = a; d1 = b;
  }

  init_k<<<1, 64, 0, stream>>>(flag);
  prep_k<<<65536, 256, 0, stream>>>(states, (const unsigned*)mask, Wf, Uf, bf_,
                                    Wb, Ub, bb_, xb16, dout, Wt, Ut, biasc, brc, flag);
  maskt_k<<<128, 256, 0, stream>>>((const unsigned char*)mask, flag, maskt);
  for (int l = 0; l < 3; ++l) {
    proj_gemm<<<dim3(256, 12), 256, 0, stream>>>(xb16, Wt + (size_t)l * 1536 * 512,
                                                 biasc + l * 1536, xp);
    gru16<<<8, 1024, LDS_BYTES, stream>>>(xp, Ut, brc, maskt, xb16, l);
    drop_k<<<65536, 256, 0, stream>>>(xb16, dout, training, sk0[l], sk1[l], l == 2);
  }
}

// Round 8
// 3790.870 us; speedup vs baseline: 1.2740x; 1.2019x over previous
//
#include <hip/hip_runtime.h>
#include <stdint.h>

typedef __attribute__((ext_vector_type(8))) short short8;
typedef __attribute__((ext_vector_type(4))) float f32x4;

// ---- workspace byte offsets (total ~141.8 MB) ----
#define XB16_OFF  0UL           // bf16 layer input/output [t*64+b][512]   32 MB
#define XP_OFF    33554432UL    // fp16 projections [t][dir][b][gate][u]   96 MB
#define WT_OFF    134217728UL   // bf16 W^T  [3][1536][512]               4.5 MB
#define UT_OFF    138936320UL   // bf16 U^T  [dir*3+l][768][256]         2.25 MB
#define BIASC_OFF 141295616UL   // fp32 input bias (+recur bias for z,r) [3][1536]
#define BRC_OFF   141314048UL   // fp32 recur bias [dir*3+l][768]
#define MASKT_OFF 141332480UL   // byte mask transposed [t][64]           32 KB
#define FLAG_OFF  141725760UL   // mask-dtype flag

#define HB_STRIDE 264           // 256 + 8 pad halves (conflict-free b128 reads)
#define HBLK (16 * HB_STRIDE)
// LDS: h-gate U^T [256][HB_STRIDE] + h state double buffer [2][16][HB_STRIDE]
#define LDS_BYTES (((size_t)256 * HB_STRIDE + 2 * HBLK) * 2)

// LDS-only barrier: h double-buffer hazards are all lgkmcnt-counted. Avoids
// __syncthreads' vmcnt(0) drain so global loads/stores ride across steps.
#define LDS_BARRIER() asm volatile("s_waitcnt lgkmcnt(0)\n\ts_barrier" ::: "memory")

// async global->LDS (16B per lane; LDS dst = wave-uniform base + lane*16)
typedef __attribute__((address_space(1))) const unsigned int* as1_u32p;
typedef __attribute__((address_space(3))) unsigned int* as3_u32p;
#define GLOBAL_TO_LDS16(g, l) \
  __builtin_amdgcn_global_load_lds((as1_u32p)(g), (as3_u32p)(l), 16, 0, 0)

// ---- threefry2x32, 20 rounds (jax partitionable mode) ----
__host__ __device__ static inline void tf2x32(unsigned k0, unsigned k1,
                                              unsigned x0, unsigned x1,
                                              unsigned* o0, unsigned* o1) {
  unsigned ks2 = k0 ^ k1 ^ 0x1BD11BDAu;
#define TFR(r) { x0 += x1; x1 = (x1 << (r)) | (x1 >> (32 - (r))); x1 ^= x0; }
  x0 += k0; x1 += k1;
  TFR(13) TFR(15) TFR(26) TFR(6)   x0 += k1;  x1 += ks2 + 1u;
  TFR(17) TFR(29) TFR(16) TFR(24)  x0 += ks2; x1 += k0 + 2u;
  TFR(13) TFR(15) TFR(26) TFR(6)   x0 += k0;  x1 += k1 + 3u;
  TFR(17) TFR(29) TFR(16) TFR(24)  x0 += k1;  x1 += ks2 + 4u;
  TFR(13) TFR(15) TFR(26) TFR(6)   x0 += ks2; x1 += k0 + 5u;
#undef TFR
  *o0 = x0; *o1 = x1;
}

__device__ static inline short f2bf(float f) {  // RNE fp32->bf16
  unsigned u = __float_as_uint(f);
  u = (u + 0x7fffu + ((u >> 16) & 1u)) >> 16;
  return (short)u;
}
__device__ static inline float bf2f(short s) {
  unsigned u = ((unsigned)(unsigned short)s) << 16;
  return __uint_as_float(u);
}
__device__ static inline float cvt_lo(unsigned d) {
  union { unsigned short u; _Float16 h; } c; c.u = (unsigned short)(d & 0xffffu);
  return (float)c.h;
}
__device__ static inline float cvt_hi(unsigned d) {
  union { unsigned short u; _Float16 h; } c; c.u = (unsigned short)(d >> 16);
  return (float)c.h;
}

__global__ void init_k(unsigned* flag) {
  if (threadIdx.x == 0) *flag = 0u;
}

// ---- prep: casts, transposes, tail copy, mask dtype detection ----
__global__ __launch_bounds__(256) void prep_k(
    const float* __restrict__ states, const unsigned* __restrict__ maskw,
    const float* __restrict__ Wf, const float* __restrict__ Uf,
    const float* __restrict__ bf_, const float* __restrict__ Wb,
    const float* __restrict__ Ub, const float* __restrict__ bb_,
    short* __restrict__ xb16, float* __restrict__ dout,
    short* __restrict__ Wt, short* __restrict__ Ut,
    float* __restrict__ biasc, float* __restrict__ brc,
    unsigned* __restrict__ flag) {
  const unsigned gid = blockIdx.x * 256 + threadIdx.x;  // 16,777,216 threads
  {  // states [b*512+t][512] -> xb16 t-major [t*64+b][512]
    unsigned c = gid & 511u, rw = gid >> 9;
    unsigned t = rw >> 6, b = rw & 63u;
    xb16[gid] = f2bf(states[(size_t)(b * 512 + t) * 512 + c]);
  }
  if (gid < 512000u) dout[16777216u + gid] = states[16777216u + gid];  // EXTRA tail
  if (gid < 2359296u) {  // W^T bf16: [l][n(1536)][k(512)]
    unsigned l = gid / 786432u, rem = gid % 786432u;
    unsigned n = rem >> 9, k = rem & 511u;
    float s = (n < 768u) ? Wf[(size_t)(l * 512 + k) * 768 + n]
                         : Wb[(size_t)(l * 512 + k) * 768 + (n - 768u)];
    Wt[gid] = f2bf(s);
  }
  if (gid < 1179648u) {  // U^T bf16: [(dir*3+l)][n(768)][k(256)]
    unsigned g = gid / 196608u, rem = gid % 196608u;
    unsigned dirv = g / 3u, l = g % 3u;
    unsigned n = rem >> 8, k = rem & 255u;
    const float* Usrc = dirv ? Ub : Uf;
    Ut[gid] = f2bf(Usrc[(size_t)(l * 256 + k) * 768 + n]);
  }
  if (gid < 4608u) {  // input bias concat [l][1536]; fold recur bias for z,r gates
    unsigned l = gid / 1536u, n = gid % 1536u;
    unsigned dirv = n / 768u, rem = n % 768u;
    const float* bsrc = dirv ? bb_ : bf_;
    float v = bsrc[(l * 2 + 0) * 768 + rem];
    if (rem < 512u) v += bsrc[(l * 2 + 1) * 768 + rem];   // z,r: additive -> fold
    biasc[gid] = v;
  }
  if (gid < 4608u) {  // recurrent bias [(dir*3+l)][768] (h-gate part used by gru)
    unsigned g = gid / 768u, n = gid % 768u;
    unsigned dirv = g / 3u, l = g % 3u;
    brc[gid] = (dirv ? bb_ : bf_)[(l * 2 + 1) * 768 + n];
  }
  if (gid < 8192u) {  // mask stored as bytes? any word >1 => yes
    if (maskw[gid] > 1u) atomicOr(flag, 1u);
  }
}

// ---- mask transpose: [b][t] (byte or word) -> bytes [t][64] ----
__global__ __launch_bounds__(256) void maskt_k(
    const unsigned char* __restrict__ mask8, const unsigned* __restrict__ flagp,
    unsigned char* __restrict__ maskt) {
  const unsigned gid = blockIdx.x * 256 + threadIdx.x;  // 32768
  const unsigned b = gid >> 9, t = gid & 511u;
  const bool mbyte = (*flagp) != 0u;
  unsigned v = mbyte ? (unsigned)mask8[gid] : ((const unsigned*)mask8)[gid];
  maskt[t * 64 + b] = v ? 1u : 0u;
}

// ---- projection GEMM: [32768,512]bf16 x [512,1536]bf16 -> fp16 + bias ----
// Staging via global_load_lds (async direct-to-LDS, 16B/lane).
// Output layout: xp[t][dir][b][gate][u] fp16:
//   half index = ((t*2+dir)*64 + b)*768 + gate*256 + u
__global__ __launch_bounds__(256) void proj_gemm(
    const short* __restrict__ A, const short* __restrict__ Bt,
    const float* __restrict__ bias, _Float16* __restrict__ C) {
  __shared__ __align__(16) short As[4096];
  __shared__ __align__(16) short Bs[4096];
  const int tid = threadIdx.x;
  const int wave = tid >> 6, lane = tid & 63;
  const int col = lane & 15, kq = lane >> 4;
  const int wr = wave >> 1, wc = wave & 1;
  const int m0 = blockIdx.x * 128, n0 = blockIdx.y * 128;
  const uint4* Aq = (const uint4*)A;
  const uint4* Bq = (const uint4*)Bt;
  f32x4 acc[4][4];
#pragma unroll
  for (int i = 0; i < 4; ++i)
#pragma unroll
    for (int j = 0; j < 4; ++j) acc[i][j] = (f32x4){0.f, 0.f, 0.f, 0.f};

  for (int kt = 0; kt < 16; ++kt) {
    const int k8 = kt * 4;
    // async stage: per wave, 64 lanes x 16B contiguous in LDS; global src per-lane
#pragma unroll
    for (int rnd = 0; rnd < 2; ++rnd) {
      const int chunk = rnd * 256 + wave * 64 + lane;
      const int row = chunk >> 2, kc = chunk & 3;
      const int base = (rnd * 256 + wave * 64) * 8;  // halves, wave-uniform
      GLOBAL_TO_LDS16(&Aq[(size_t)(m0 + row) * 64 + k8 + kc], As + base);
      GLOBAL_TO_LDS16(&Bq[(size_t)(n0 + row) * 64 + k8 + kc], Bs + base);
    }
    __syncthreads();   // drains vmcnt (global_load_lds) + barrier
    short8 af[4], bfv[4];
#pragma unroll
    for (int i = 0; i < 4; ++i)
      af[i] = *(const short8*)(As + (wr * 64 + i * 16 + col) * 32 + kq * 8);
#pragma unroll
    for (int j = 0; j < 4; ++j)
      bfv[j] = *(const short8*)(Bs + (wc * 64 + j * 16 + col) * 32 + kq * 8);
#pragma unroll
    for (int i = 0; i < 4; ++i)
#pragma unroll
      for (int j = 0; j < 4; ++j)
        acc[i][j] = __builtin_amdgcn_mfma_f32_16x16x32_bf16(af[i], bfv[j], acc[i][j], 0, 0, 0);
    __syncthreads();
  }
  // m = m0 + wr*64 + (i*16+kq*4+r): t = (m0>>6)+wr (const), b = i*16+kq*4+r
#pragma unroll
  for (int j = 0; j < 4; ++j) {
    const int cg = n0 + wc * 64 + j * 16 + col;
    const float bv = bias[cg];
    const int dirv = cg / 768, rem = cg % 768;
    const int gate = rem >> 8, u = rem & 255;
    const size_t cbase =
        ((size_t)(((m0 >> 6) + wr) * 2 + dirv)) * 49152 + gate * 256 + u;
#pragma unroll
    for (int i = 0; i < 4; ++i) {
#pragma unroll
      for (int r = 0; r < 4; ++r)
        C[cbase + (size_t)(i * 16 + kq * 4 + r) * 768] = (_Float16)(acc[i][j][r] + bv);
    }
  }
}

// ---- recurrent kernel: 8 blocks x 1024 threads (16 waves, 4 waves/SIMD) ----
// TRANSPOSED mapping: D[m=unit][n=batch]. Wave w owns units [w*16,w*16+16);
// A = U^T (static: z/r frags in regs = 64 AGPR, h-gate staged in LDS), B =
// h(t-1) from LDS. Register budget is EXACTLY full at 64 VGPR + 64 AGPR =
// 128 = 4 waves/SIMD; any residency addition drops occupancy (r6/r7 lesson).
// Thread (col,quad) produces units w*16+quad*4..+3 for batch row col ->
// contiguous I/O: 3 b64 xp loads (one base + imm offsets), 1 b64 ds_write,
// 1 b64 y store, 1 mask byte, 2 v_cvt_pk_bf16_f32 packs.
__global__ __launch_bounds__(1024, 4) void gru16(
    const _Float16* __restrict__ xp, const short* __restrict__ UtAll,
    const float* __restrict__ brcAll, const unsigned char* __restrict__ maskt,
    short* __restrict__ yout, int layer) {
  extern __shared__ short lds[];
  short* hgate = lds;                       // [256][HB_STRIDE] h-gate U^T
  short* hbuf  = lds + 256 * HB_STRIDE;     // [2][16][HB_STRIDE] h state (bf16)

  const int bid = blockIdx.x;
  const int dir = bid >> 2;
  const int b0 = (bid & 3) * 16;
  const int tid = threadIdx.x;
  const int wave = tid >> 6, lane = tid & 63;
  const int col = lane & 15, quad = lane >> 4;
  const int u0 = wave * 16 + quad * 4;      // first owned unit
  const short* Ut = UtAll + (size_t)(dir * 3 + layer) * 768 * 256;
  const float* brc = brcAll + (dir * 3 + layer) * 768;

  // stage h-gate U^T rows [512,768) -> hgate, zero h buffers
  const short* Uth = Ut + 512 * 256;
  for (int c = tid; c < 8192; c += 1024) {
    int row = c >> 5, q = c & 31;
    *(uint4*)(hgate + row * HB_STRIDE + q * 8) = *(const uint4*)(Uth + row * 256 + q * 8);
  }
  for (int i = tid; i < 2 * HBLK; i += 1024) hbuf[i] = 0;

  // resident z/r A-fragments: lane (col,quad) holds A[m=col][k=quad*8+j]
  // = U^T[wave*16+col][ks*32+quad*8+j]
  short8 zA[8], rA[8];
#pragma unroll
  for (int ks = 0; ks < 8; ++ks) {
    zA[ks] = *(const short8*)(Ut + (size_t)(wave * 16 + col) * 256 + ks * 32 + quad * 8);
    rA[ks] = *(const short8*)(Ut + (size_t)(256 + wave * 16 + col) * 256 + ks * 32 + quad * 8);
  }
  f32x4 brh;
#pragma unroll
  for (int r = 0; r < 4; ++r) brh[r] = brc[512 + u0 + r];

  // xp addressing (bytes): base = ((t*2+dir)*64 + b)*1536 + u0-within-dir*2
  //   z at +0, r at +512, h at +1024 (imm offsets)
  const int t0 = dir ? 511 : 0;
  const int tstep = dir ? -1 : 1;
  const char* xpb = (const char*)xp;
  const int gb = b0 + col;                  // global batch row for this thread
  unsigned xaddr = (unsigned)(((t0 * 2 + dir) * 64 + gb) * 1536 + wave * 32 + quad * 8);
  const int xstep = tstep * 196608;         // 2*64*1536

  // LDS lane offsets (halves)
  const short* hgA = hgate + (wave * 16 + col) * HB_STRIDE + quad * 8;
  const int rd_lane = col * HB_STRIDE + quad * 8;
  const int wr_lane = col * HB_STRIDE + u0;

  // y addressing (bytes): (t*64+b)*1024 + dir*512 + u0*2
  unsigned yoff = (unsigned)((t0 * 64 + gb) * 1024 + dir * 512 + u0 * 2);
  const int ystep = tstep * 65536;
  int moff = t0 * 64 + gb;

  // prologue prefetch for s=0
  uint2 pz, pr, ph;
  unsigned pm;
  pz = *(const uint2*)(xpb + xaddr);
  pr = *(const uint2*)(xpb + xaddr + 512);
  ph = *(const uint2*)(xpb + xaddr + 1024);
  pm = maskt[moff];

  float hp[4] = {0.f, 0.f, 0.f, 0.f};
  __syncthreads();

  for (int s = 0; s < 512; ++s) {
    // init accumulators from prefetched projections (z,r) and recur bias (h)
    f32x4 az, ar, ah;
    az[0] = cvt_lo(pz.x); az[1] = cvt_hi(pz.x);
    az[2] = cvt_lo(pz.y); az[3] = cvt_hi(pz.y);
    ar[0] = cvt_lo(pr.x); ar[1] = cvt_hi(pr.x);
    ar[2] = cvt_lo(pr.y); ar[3] = cvt_hi(pr.y);
    ah = brh;
    float xh[4];
    xh[0] = cvt_lo(ph.x); xh[1] = cvt_hi(ph.x);
    xh[2] = cvt_lo(ph.y); xh[3] = cvt_hi(ph.y);
    const bool mv = (pm != 0u);
    // issue next-step prefetch (consumed at next init)
    if (s < 511) {
      xaddr += xstep;
      pz = *(const uint2*)(xpb + xaddr);
      pr = *(const uint2*)(xpb + xaddr + 512);
      ph = *(const uint2*)(xpb + xaddr + 1024);
      moff += tstep * 64;
      pm = maskt[moff];
    }

    // recurrent matmul: A=U^T (z/r regs, h LDS), B=h(t-1) from LDS
    const short* hrd = hbuf + (s & 1) * HBLK + rd_lane;
#pragma unroll
    for (int ks = 0; ks < 8; ++ks) {
      short8 hbv = *(const short8*)(hrd + ks * 32);
      short8 hg  = *(const short8*)(hgA + ks * 32);
      az = __builtin_amdgcn_mfma_f32_16x16x32_bf16(zA[ks], hbv, az, 0, 0, 0);
      ar = __builtin_amdgcn_mfma_f32_16x16x32_bf16(rA[ks], hbv, ar, 0, 0, 0);
      ah = __builtin_amdgcn_mfma_f32_16x16x32_bf16(hg,     hbv, ah, 0, 0, 0);
    }

    // epilogue: 4 consecutive units for one batch row
    float hn[4];
#pragma unroll
    for (int r = 0; r < 4; ++r) {
      float z  = 1.f / (1.f + __builtin_amdgcn_exp2f(az[r] * -1.44269504f));
      float rr = 1.f / (1.f + __builtin_amdgcn_exp2f(ar[r] * -1.44269504f));
      float pre = xh[r] + rr * ah[r];
      float hc = 1.f - 2.f / (__builtin_amdgcn_exp2f(pre * 2.88539008f) + 1.f);
      float hpv = hp[r];
      float v = hc + z * (hpv - hc);
      hn[r] = mv ? v : hpv;
      hp[r] = hn[r];
    }
    uint2 packed;
    asm("v_cvt_pk_bf16_f32 %0, %1, %2" : "=v"(packed.x) : "v"(hn[0]), "v"(hn[1]));
    asm("v_cvt_pk_bf16_f32 %0, %1, %2" : "=v"(packed.y) : "v"(hn[2]), "v"(hn[3]));
    *(uint2*)(hbuf + ((s & 1) ^ 1) * HBLK + wr_lane) = packed;
    // LDS-only barrier (no vmcnt drain): global ops stay in flight
    LDS_BARRIER();
    // y store AFTER the barrier: trims the pre-barrier tail; store rides
    // across the next step (no vmcnt wait on it anywhere in the loop)
    *(uint2*)((char*)yout + yoff) = packed;
    yoff += ystep;
  }
}

// ---- dropout (JAX threefry partitionable); j == gid (t-major) ----
__global__ __launch_bounds__(256) void drop_k(
    short* __restrict__ xb16, float* __restrict__ dout,
    const int* __restrict__ training, unsigned k0, unsigned k1, int last) {
  const unsigned gid = blockIdx.x * 256 + threadIdx.x;
  float v = bf2f(xb16[gid]);
  unsigned y0, y1;
  tf2x32(k0, k1, 0u, gid, &y0, &y1);
  unsigned bits = y0 ^ y1;
  float u = __uint_as_float((bits >> 9) | 0x3f800000u) - 1.0f;
  bool keep = u < 0.9f;
  int tr = *training;
  float ov = tr ? (keep ? v * (1.0f / 0.9f) : 0.0f) : v;
  if (last) {
    unsigned r = gid >> 9, c = gid & 511u;
    unsigned t = r >> 6, b = r & 63u;
    dout[(size_t)(b * 512 + t) * 512 + c] = ov;
  } else {
    xb16[gid] = f2bf(ov);
  }
}

extern "C" void kernel_launch(void* const* d_in, const int* in_sizes, int n_in,
                              void* d_out, int out_size, void* d_ws, size_t ws_size,
                              hipStream_t stream) {
  (void)in_sizes; (void)n_in; (void)out_size; (void)ws_size;
  const float* states = (const float*)d_in[0];
  const void*  mask   = d_in[1];
  const int*   training = (const int*)d_in[3];
  const float* Wf = (const float*)d_in[4];
  const float* Uf = (const float*)d_in[5];
  const float* bf_ = (const float*)d_in[6];
  const float* Wb = (const float*)d_in[7];
  const float* Ub = (const float*)d_in[8];
  const float* bb_ = (const float*)d_in[9];
  char* ws = (char*)d_ws;

  short* xb16   = (short*)(ws + XB16_OFF);
  _Float16* xp  = (_Float16*)(ws + XP_OFF);
  short* Wt     = (short*)(ws + WT_OFF);
  short* Ut     = (short*)(ws + UT_OFF);
  float* biasc  = (float*)(ws + BIASC_OFF);
  float* brc    = (float*)(ws + BRC_OFF);
  unsigned char* maskt = (unsigned char*)(ws + MASKT_OFF);
  unsigned* flag = (unsigned*)(ws + FLAG_OFF);
  float* dout = (float*)d_out;

  // allow >64KB dynamic LDS for gru16 (idempotent; not a stream op)
  hipFuncSetAttribute((const void*)gru16,
                      hipFuncAttributeMaxDynamicSharedMemorySize, (int)LDS_BYTES);

  // threefry key chain: key(1234); per layer: dkey,sk = split(dkey)
  unsigned d0 = 0u, d1 = 1234u, sk0[3], sk1[3];
  for (int l = 0; l < 3; ++l) {
    unsigned a, b, c, d;
    tf2x32(d0, d1, 0u, 0u, &a, &b);   // new dkey
    tf2x32(d0, d1, 0u, 1u, &c, &d);   // subkey
    sk0[l] = c; sk1[l] = d;
    d0 = a; d1 = b;
  }

  init_k<<<1, 64, 0, stream>>>(flag);
  prep_k<<<65536, 256, 0, stream>>>(states, (const unsigned*)mask, Wf, Uf, bf_,
                                    Wb, Ub, bb_, xb16, dout, Wt, Ut, biasc, brc, flag);
  maskt_k<<<128, 256, 0, stream>>>((const unsigned char*)mask, flag, maskt);
  for (int l = 0; l < 3; ++l) {
    proj_gemm<<<dim3(256, 12), 256, 0, stream>>>(xb16, Wt + (size_t)l * 1536 * 512,
                                                 biasc + l * 1536, xp);
    gru16<<<8, 1024, LDS_BYTES, stream>>>(xp, Ut, brc, maskt, xb16, l);
    drop_k<<<65536, 256, 0, stream>>>(xb16, dout, training, sk0[l], sk1[l], l == 2);
  }
}